// Round 1
// baseline (148.398 us; speedup 1.0000x reference)
//
#include <hip/hip_runtime.h>

#define D_MODEL 1024
#define TPB_TOKENS 16

typedef float vfloat4 __attribute__((ext_vector_type(4)));

// ---------------------------------------------------------------------------
// out[tok][d] = t^2 * A[d] + t * B[d] + C[d]   (t = float(N_tokens[tok]))
//   A[d] = W[d,0]+W[d,3]+W[d,6]+W[d,9]
//   B[d] = W[d,1]+W[d,2]+2W[d,4]+2W[d,8]+2W[d,10]
//   C[d] = W[d,2]+2W[d,4]-W[d,5]+W[d,8]+W[d,10]+bias[d]
//
// Two-kernel structure:
//   kernel 1 (1 block): fold W[1024,12]+bias into A/B/C [3*1024 f32 = 12 KiB]
//     in d_ws. Runs once per launch (~2 us), removes the per-block W
//     preprocessing that previously ran 4096x (47M stride-48B loads, W+bias
//     52 KiB > 32 KiB L1 -> L2-latency-exposed prologue in every wave).
//   kernel 2 (2048 blocks): prologue = 3 coalesced dwordx4 loads of
//     L2-resident coeffs, then pure streaming nt-store of 16 tokens/block.
// ---------------------------------------------------------------------------

__global__ __launch_bounds__(256) void n2_coeffs_kernel(
    const float* __restrict__ W,
    const float* __restrict__ bias,
    float* __restrict__ coeffs)   // [3][D_MODEL]: A, B, C
{
    const int d0 = threadIdx.x * 4;   // 256 threads cover D_MODEL=1024

    // Thread's 4 rows of W are 48 contiguous floats (192 B, 16B-aligned).
    float wv[48];
    const vfloat4* wp = (const vfloat4*)(W + (size_t)d0 * 12);
#pragma unroll
    for (int k = 0; k < 12; ++k)
        ((vfloat4*)wv)[k] = wp[k];

    const vfloat4 bb = *(const vfloat4*)(bias + d0);

    vfloat4 A, B, C;
#pragma unroll
    for (int j = 0; j < 4; ++j) {
        const float* w = wv + j * 12;
        float w0 = w[0], w1 = w[1], w2 = w[2], w3 = w[3];
        float w4 = w[4], w5 = w[5], w6 = w[6];
        float w8 = w[8], w9 = w[9], w10 = w[10];
        // Keep exact FP ordering of the verified previous kernel.
        A[j] = (w0 + w3) + (w6 + w9);
        B[j] = w1 + w2 + 2.0f * w4 + 2.0f * w8 + 2.0f * w10;
        C[j] = w2 + 2.0f * w4 - w5 + w8 + w10 + bb[j];
    }

    *(vfloat4*)(coeffs + d0)               = A;
    *(vfloat4*)(coeffs + D_MODEL + d0)     = B;
    *(vfloat4*)(coeffs + 2 * D_MODEL + d0) = C;
}

__global__ __launch_bounds__(256) void n2_embed_stream_kernel(
    const int* __restrict__ toks,
    const float* __restrict__ coeffs,
    float* __restrict__ out,
    int n_tokens)
{
    const int d0 = threadIdx.x * 4;

    // Coalesced, L2-resident: 3 x global_load_dwordx4 at thread*16B.
    const vfloat4 A = *(const vfloat4*)(coeffs + d0);
    const vfloat4 B = *(const vfloat4*)(coeffs + D_MODEL + d0);
    const vfloat4 C = *(const vfloat4*)(coeffs + 2 * D_MODEL + d0);

    const int tok_begin = blockIdx.x * TPB_TOKENS;

    // Token values are block-uniform -> compiler emits scalar loads.
    float tvals[TPB_TOKENS];
#pragma unroll
    for (int i = 0; i < TPB_TOKENS; ++i) {
        int tok = tok_begin + i;
        tvals[i] = (tok < n_tokens) ? (float)toks[tok] : 0.0f;
    }

#pragma unroll
    for (int i = 0; i < TPB_TOKENS; ++i) {
        int tok = tok_begin + i;
        if (tok >= n_tokens) break;
        float t = tvals[i];
        float t2 = t * t;
        vfloat4 o;
        o.x = fmaf(t2, A.x, fmaf(t, B.x, C.x));
        o.y = fmaf(t2, A.y, fmaf(t, B.y, C.y));
        o.z = fmaf(t2, A.z, fmaf(t, B.z, C.z));
        o.w = fmaf(t2, A.w, fmaf(t, B.w, C.w));
        // Streaming store: wave writes 1 KiB contiguous per instruction.
        __builtin_nontemporal_store(o, (vfloat4*)(out + (size_t)tok * D_MODEL + d0));
    }
}

// Fallback (ws too small): previous verified single-kernel form, 16 tok/block.
__global__ __launch_bounds__(256) void n2_embed_fused_kernel(
    const int* __restrict__ toks,
    const float* __restrict__ W,
    const float* __restrict__ bias,
    float* __restrict__ out,
    int n_tokens)
{
    const int d0 = threadIdx.x * 4;

    float A[4], B[4], C[4];
#pragma unroll
    for (int j = 0; j < 4; ++j) {
        const float* w = W + (size_t)(d0 + j) * 12;
        float w0 = w[0], w1 = w[1], w2 = w[2], w3 = w[3];
        float w4 = w[4], w5 = w[5], w6 = w[6];
        float w8 = w[8], w9 = w[9], w10 = w[10];
        A[j] = (w0 + w3) + (w6 + w9);
        B[j] = w1 + w2 + 2.0f * w4 + 2.0f * w8 + 2.0f * w10;
        C[j] = w2 + 2.0f * w4 - w5 + w8 + w10 + bias[d0 + j];
    }

    const int tok_begin = blockIdx.x * TPB_TOKENS;
    float tvals[TPB_TOKENS];
#pragma unroll
    for (int i = 0; i < TPB_TOKENS; ++i) {
        int tok = tok_begin + i;
        tvals[i] = (tok < n_tokens) ? (float)toks[tok] : 0.0f;
    }

#pragma unroll
    for (int i = 0; i < TPB_TOKENS; ++i) {
        int tok = tok_begin + i;
        if (tok >= n_tokens) break;
        float t = tvals[i];
        float t2 = t * t;
        vfloat4 o;
        o.x = fmaf(t2, A[0], fmaf(t, B[0], C[0]));
        o.y = fmaf(t2, A[1], fmaf(t, B[1], C[1]));
        o.z = fmaf(t2, A[2], fmaf(t, B[2], C[2]));
        o.w = fmaf(t2, A[3], fmaf(t, B[3], C[3]));
        __builtin_nontemporal_store(o, (vfloat4*)(out + (size_t)tok * D_MODEL + d0));
    }
}

extern "C" void kernel_launch(void* const* d_in, const int* in_sizes, int n_in,
                              void* d_out, int out_size, void* d_ws, size_t ws_size,
                              hipStream_t stream) {
    const int* toks = (const int*)d_in[0];       // N_tokens [4,8192] (int32 view)
    const float* W = (const float*)d_in[1];      // [1024,12]
    const float* bias = (const float*)d_in[2];   // [1024]
    float* out = (float*)d_out;                  // [4,8192,1024] fp32

    int n_tokens = out_size / D_MODEL;           // 32768
    int blocks = (n_tokens + TPB_TOKENS - 1) / TPB_TOKENS;  // 2048

    if (d_ws != nullptr && ws_size >= 3 * D_MODEL * sizeof(float)) {
        float* coeffs = (float*)d_ws;
        n2_coeffs_kernel<<<1, 256, 0, stream>>>(W, bias, coeffs);
        n2_embed_stream_kernel<<<blocks, 256, 0, stream>>>(toks, coeffs, out, n_tokens);
    } else {
        n2_embed_fused_kernel<<<blocks, 256, 0, stream>>>(toks, W, bias, out, n_tokens);
    }
}

// Round 2
// 141.838 us; speedup vs baseline: 1.0463x; 1.0463x over previous
//
#include <hip/hip_runtime.h>

#define D_MODEL 1024
#define TPB_TOKENS 32

typedef float vfloat4 __attribute__((ext_vector_type(4)));

// ---------------------------------------------------------------------------
// out[tok][d] = t^2 * A[d] + t * B[d] + C[d]   (t = float(N_tokens[tok]))
//   A[d] = W[d,0]+W[d,3]+W[d,6]+W[d,9]
//   B[d] = W[d,1]+W[d,2]+2W[d,4]+2W[d,8]+2W[d,10]
//   C[d] = W[d,2]+2W[d,4]-W[d,5]+W[d,8]+W[d,10]+bias[d]
//
// Single fused kernel (R1's coeff pre-kernel was a null result: prologue was
// never the bottleneck, and the extra serial launch cost ~5 us).
//
// R2 change under test: PLAIN vector stores instead of nontemporal.
// Evidence: the harness's own 512 MiB poison fill sustains 6.24 TB/s with
// plain streaming stores and ~zero FETCH_SIZE (no read-for-write on full,
// aligned lines), while our nt-store kernel ran at ~2.3 TB/s with an
// identical address pattern (4 KiB contiguous per block-step). Theory: the
// nt flag bypasses L2 write-combining into a slower DRAM write path.
//
// Prologue: thread's 4 W-rows are 48 contiguous floats -> 12 x float4 loads,
// L2-resident after first touch (W+bias = 52 KiB). Negligible vs store time.
// ---------------------------------------------------------------------------
__global__ __launch_bounds__(256) void n2_embed_kernel(
    const int* __restrict__ toks,
    const float* __restrict__ W,
    const float* __restrict__ bias,
    float* __restrict__ out,
    int n_tokens)
{
    const int d0 = threadIdx.x * 4;   // 256 threads cover D_MODEL = 1024

    // Vectorized W load: 12 x global_load_dwordx4, fully coalesced per wave.
    float wv[48];
    const vfloat4* wp = (const vfloat4*)(W + (size_t)d0 * 12);
#pragma unroll
    for (int k = 0; k < 12; ++k)
        ((vfloat4*)wv)[k] = wp[k];

    const vfloat4 bb = *(const vfloat4*)(bias + d0);

    float A[4], B[4], C[4];
#pragma unroll
    for (int j = 0; j < 4; ++j) {
        const float* w = wv + j * 12;
        float w0 = w[0], w1 = w[1], w2 = w[2], w3 = w[3];
        float w4 = w[4], w5 = w[5], w6 = w[6];
        float w8 = w[8], w9 = w[9], w10 = w[10];
        // Same FP ordering as the verified baseline.
        A[j] = (w0 + w3) + (w6 + w9);
        B[j] = w1 + w2 + 2.0f * w4 + 2.0f * w8 + 2.0f * w10;
        C[j] = w2 + 2.0f * w4 - w5 + w8 + w10 + bb[j];
    }

    const int tok_begin = blockIdx.x * TPB_TOKENS;

    // Token values are block-uniform -> scalar loads, issued up front.
    float tvals[TPB_TOKENS];
#pragma unroll
    for (int i = 0; i < TPB_TOKENS; ++i) {
        int tok = tok_begin + i;
        tvals[i] = (tok < n_tokens) ? (float)toks[tok] : 0.0f;
    }

#pragma unroll
    for (int i = 0; i < TPB_TOKENS; ++i) {
        int tok = tok_begin + i;
        if (tok >= n_tokens) break;
        float t = tvals[i];
        float t2 = t * t;
        vfloat4 o;
        o.x = fmaf(t2, A[0], fmaf(t, B[0], C[0]));
        o.y = fmaf(t2, A[1], fmaf(t, B[1], C[1]));
        o.z = fmaf(t2, A[2], fmaf(t, B[2], C[2]));
        o.w = fmaf(t2, A[3], fmaf(t, B[3], C[3]));
        // PLAIN store (not nontemporal): wave writes 1 KiB contiguous per
        // instruction, block writes 4 KiB per step — full aligned lines,
        // same pattern the 6.24 TB/s poison fill uses.
        *(vfloat4*)(out + (size_t)tok * D_MODEL + d0) = o;
    }
}

extern "C" void kernel_launch(void* const* d_in, const int* in_sizes, int n_in,
                              void* d_out, int out_size, void* d_ws, size_t ws_size,
                              hipStream_t stream) {
    const int* toks = (const int*)d_in[0];       // N_tokens [4,8192] (int32 view)
    const float* W = (const float*)d_in[1];      // [1024,12]
    const float* bias = (const float*)d_in[2];   // [1024]
    float* out = (float*)d_out;                  // [4,8192,1024] fp32

    int n_tokens = out_size / D_MODEL;           // 32768
    int blocks = (n_tokens + TPB_TOKENS - 1) / TPB_TOKENS;  // 1024

    n2_embed_kernel<<<blocks, 256, 0, stream>>>(toks, W, bias, out, n_tokens);
}